// Round 1
// baseline (15.109 us; speedup 1.0000x reference)
//
#include <hip/hip_runtime.h>

// CentersDistance: logits[c][q] = -||centers[c] - inputs[q]||^2
// inputs:  [4096][128] f32
// centers: [ 256][128] f32
// out:     [ 256][4096] f32
//
// GEMM-shaped: M=256 (c), N=4096 (q), K=128 (d). No fp32 MFMA on CDNA4 ->
// vector-ALU register-tiled kernel. Block = 256 thr, tile 64c x 64q, full K
// staged transposed in LDS ([k][m] layout so inner loop uses ds_read_b128).

constexpr int QN = 4096;
constexpr int CN = 256;
constexpr int DK = 128;
constexpr int BM = 64;   // centers per block
constexpr int BN = 64;   // queries per block

__global__ __launch_bounds__(256) void centers_dist(
    const float* __restrict__ inputs,
    const float* __restrict__ centers,
    float* __restrict__ out)
{
    __shared__ float As[DK][BM];  // As[k][cm] = centers[c0+cm][k]
    __shared__ float Bs[DK][BN];  // Bs[k][qn] = inputs [q0+qn][k]

    const int tid = threadIdx.x;          // 0..255
    const int c0 = blockIdx.x * BM;       // 0..3  * 64
    const int q0 = blockIdx.y * BN;       // 0..63 * 64

    // Stage both tiles, transposing into [k][m].
    // idx walks 64 rows x 32 float4-columns; row = idx & 63 keeps the 64
    // lanes of a wave on distinct rows -> transposed ds_write addresses are
    // consecutive (banks row%32, 2-way = free). Global reads are 16B/lane at
    // 512B stride — scattered per-instr but the tile is fully consumed, so
    // L1/L2 absorb it (one-time 64KB/block cost).
    #pragma unroll
    for (int it = 0; it < 8; ++it) {
        int idx  = tid + it * 256;        // 0..2047
        int row  = idx & 63;
        int col4 = idx >> 6;              // 0..31
        float4 a = *reinterpret_cast<const float4*>(&centers[(c0 + row) * DK + col4 * 4]);
        float4 b = *reinterpret_cast<const float4*>(&inputs [(q0 + row) * DK + col4 * 4]);
        As[col4 * 4 + 0][row] = a.x;
        As[col4 * 4 + 1][row] = a.y;
        As[col4 * 4 + 2][row] = a.z;
        As[col4 * 4 + 3][row] = a.w;
        Bs[col4 * 4 + 0][row] = b.x;
        Bs[col4 * 4 + 1][row] = b.y;
        Bs[col4 * 4 + 2][row] = b.z;
        Bs[col4 * 4 + 3][row] = b.w;
    }
    __syncthreads();

    // 16x16 thread grid, each thread owns a 4c x 4q micro-tile.
    const int tx = tid & 15;              // q group
    const int ty = tid >> 4;              // c group
    const int cm = ty * 4;
    const int qn = tx * 4;

    float acc[4][4] = {};                 // accumulates -(dist^2)
    #pragma unroll 4
    for (int k = 0; k < DK; ++k) {
        float4 a = *reinterpret_cast<const float4*>(&As[k][cm]);  // broadcast x16 lanes
        float4 b = *reinterpret_cast<const float4*>(&Bs[k][qn]);  // 2-way bank = free
        float av[4] = {a.x, a.y, a.z, a.w};
        float bv[4] = {b.x, b.y, b.z, b.w};
        #pragma unroll
        for (int i = 0; i < 4; ++i)
            #pragma unroll
            for (int j = 0; j < 4; ++j) {
                float d = av[i] - bv[j];
                acc[i][j] = fmaf(-d, d, acc[i][j]);  // fold the negation in
            }
    }

    // Coalesced stores: per wave, 4 c-rows x 256B contiguous each.
    #pragma unroll
    for (int i = 0; i < 4; ++i) {
        float4 v = make_float4(acc[i][0], acc[i][1], acc[i][2], acc[i][3]);
        *reinterpret_cast<float4*>(&out[(c0 + cm + i) * QN + q0 + qn]) = v;
    }
}

extern "C" void kernel_launch(void* const* d_in, const int* in_sizes, int n_in,
                              void* d_out, int out_size, void* d_ws, size_t ws_size,
                              hipStream_t stream) {
    const float* inputs  = (const float*)d_in[0];   // [4096][128]
    const float* centers = (const float*)d_in[1];   // [ 256][128]
    float* out = (float*)d_out;                     // [ 256][4096]

    dim3 grid(CN / BM, QN / BN);                    // 4 x 64 = 256 blocks (1/CU)
    centers_dist<<<grid, dim3(256), 0, stream>>>(inputs, centers, out);
}

// Round 2
// 12.535 us; speedup vs baseline: 1.2053x; 1.2053x over previous
//
#include <hip/hip_runtime.h>
#include <hip/hip_bf16.h>

// CentersDistance: logits[c][q] = -||centers[c] - inputs[q]||^2
//                             = 2*dot(c,q) - ||c||^2 - ||q||^2
// inputs:  [4096][128] f32,  centers: [256][128] f32,  out: [256][4096] f32
//
// Cross-term via bf16 MFMA (16x16x32), norms in fp32. No LDS tiles — both
// operands are L2/L3-resident (2 MB + 128 KB), fragments loaded straight
// from global and converted fp32->bf16 in-register (guideline: don't stage
// what cache-fits). LDS only holds the 1 KB of row-norm partials.

typedef __attribute__((ext_vector_type(8))) short short8;  // 8 bf16 = 4 VGPR
typedef __attribute__((ext_vector_type(4))) float f32x4;

constexpr int QN = 4096;
constexpr int CN = 256;
constexpr int DK = 128;
constexpr int BM = 64;   // centers per block
constexpr int BN = 64;   // queries per block

static __device__ inline short f2bf(float x) {
    __hip_bfloat16 h = __float2bfloat16(x);   // RNE
    return __builtin_bit_cast(short, h);
}

__global__ __launch_bounds__(256) void centers_dist_mfma(
    const float* __restrict__ inputs,
    const float* __restrict__ centers,
    float* __restrict__ out)
{
    // part[0..63][.]  = q-row sum-of-squares halves (rows q0..q0+63)
    // part[64..127][.] = c-row halves               (rows c0..c0+63)
    __shared__ float part[128][2];

    const int tid = threadIdx.x;
    const int c0 = blockIdx.x * BM;
    const int q0 = blockIdx.y * BN;

    // ---- norm partials: each thread sums one half-row (64 floats, fp32) ----
    {
        int row  = tid >> 1;
        int half = tid & 1;
        const float* src = (row < 64) ? &inputs[(q0 + row) * DK]
                                      : &centers[(c0 + row - 64) * DK];
        const float4* s4 = reinterpret_cast<const float4*>(src + half * 64);
        float s = 0.f;
        #pragma unroll
        for (int i = 0; i < 16; ++i) {
            float4 v = s4[i];
            s += v.x * v.x + v.y * v.y + v.z * v.z + v.w * v.w;
        }
        part[row][half] = s;
    }
    // no barrier yet — norms are only read in the epilogue

    // ---- MFMA cross-term: wave quadrants of the 64x64 tile ----
    const int lane = tid & 63;
    const int wid  = tid >> 6;      // 0..3
    const int wr   = wid >> 1;      // c-half
    const int wc   = wid & 1;       // q-half
    const int lr   = lane & 15;     // fragment row (M for A, N for B^T)
    const int lk   = (lane >> 4) * 8;  // k-subgroup offset (8 consecutive k)

    f32x4 acc[2][2] = {};           // acc[fm][fn], 16x16 each

    #pragma unroll
    for (int ks = 0; ks < 4; ++ks) {            // K = 4 steps of 32
        short8 af[2], bfr[2];
        #pragma unroll
        for (int fm = 0; fm < 2; ++fm) {
            const float* p = &centers[(c0 + wr * 32 + fm * 16 + lr) * DK + ks * 32 + lk];
            float4 v0 = *reinterpret_cast<const float4*>(p);
            float4 v1 = *reinterpret_cast<const float4*>(p + 4);
            af[fm] = short8{f2bf(v0.x), f2bf(v0.y), f2bf(v0.z), f2bf(v0.w),
                            f2bf(v1.x), f2bf(v1.y), f2bf(v1.z), f2bf(v1.w)};
        }
        #pragma unroll
        for (int fn = 0; fn < 2; ++fn) {
            const float* p = &inputs[(q0 + wc * 32 + fn * 16 + lr) * DK + ks * 32 + lk];
            float4 v0 = *reinterpret_cast<const float4*>(p);
            float4 v1 = *reinterpret_cast<const float4*>(p + 4);
            bfr[fn] = short8{f2bf(v0.x), f2bf(v0.y), f2bf(v0.z), f2bf(v0.w),
                             f2bf(v1.x), f2bf(v1.y), f2bf(v1.z), f2bf(v1.w)};
        }
        #pragma unroll
        for (int fm = 0; fm < 2; ++fm)
            #pragma unroll
            for (int fn = 0; fn < 2; ++fn)
                acc[fm][fn] = __builtin_amdgcn_mfma_f32_16x16x32_bf16(
                    af[fm], bfr[fn], acc[fm][fn], 0, 0, 0);
    }

    __syncthreads();   // norm partials now visible

    // ---- epilogue: 2*dot - cn - qn ----
    // D-frag mapping (verified m89/m91): col = lane&15, row = (lane>>4)*4 + j
    #pragma unroll
    for (int fm = 0; fm < 2; ++fm) {
        #pragma unroll
        for (int fn = 0; fn < 2; ++fn) {
            f32x4 a = acc[fm][fn];
            int q_loc = wc * 32 + fn * 16 + lr;
            float qn = part[q_loc][0] + part[q_loc][1];
            #pragma unroll
            for (int j = 0; j < 4; ++j) {
                int c_loc = wr * 32 + fm * 16 + (lane >> 4) * 4 + j;
                float cn = part[64 + c_loc][0] + part[64 + c_loc][1];
                out[(c0 + c_loc) * QN + (q0 + q_loc)] = 2.f * a[j] - cn - qn;
            }
        }
    }
}

extern "C" void kernel_launch(void* const* d_in, const int* in_sizes, int n_in,
                              void* d_out, int out_size, void* d_ws, size_t ws_size,
                              hipStream_t stream) {
    const float* inputs  = (const float*)d_in[0];   // [4096][128]
    const float* centers = (const float*)d_in[1];   // [ 256][128]
    float* out = (float*)d_out;                     // [ 256][4096]

    dim3 grid(CN / BM, QN / BN);                    // 4 x 64 = 256 blocks (1/CU)
    centers_dist_mfma<<<grid, dim3(256), 0, stream>>>(inputs, centers, out);
}